// Round 6
// baseline (2114.936 us; speedup 1.0000x reference)
//
#include <hip/hip_runtime.h>
#include <hip/hip_bf16.h>
#include <math.h>

#define BB 64
#define SS 64
#define VV 8
#define WW 256
#define DD 8
#define BS (BB*SS)        // 4096
#define BSV (BB*SS*VV)    // 32768

typedef __attribute__((ext_vector_type(8))) short s8v;
typedef __attribute__((ext_vector_type(4))) float f4v;

__device__ __forceinline__ short f2b(float f) {
    __hip_bfloat16 h = __float2bfloat16(f);
    return *reinterpret_cast<short*>(&h);
}
__device__ __forceinline__ float b2f(short s) {
    __hip_bfloat16 h = *reinterpret_cast<__hip_bfloat16*>(&s);
    return __bfloat162float(h);
}

// ---------------------------------------------------------------------------
// bf16 MFMA GEMM, BK=64: C[M,N] = act(A[M,K] @ B[K,N] + bias) (+ res)
// A bf16 [M,K]. Bt bf16 [N,K]. LDS rows stride 72 shorts (144B: 2-way free).
// Dual output: Cf fp32 (ldc) and/or Cb/Cb2 bf16 (ldc/ldc2).
// ---------------------------------------------------------------------------
template<int TM, int TN, int WM, int WN, bool OUTBF>
__global__ __launch_bounds__(256) void gemm_mfma(
    const short* __restrict__ A, const short* __restrict__ Bt,
    const float* __restrict__ bias, const float* __restrict__ res,
    float* __restrict__ Cf, short* __restrict__ Cb, short* __restrict__ Cb2,
    int M, int N, int K, int ldc, int ldc2, int relu)
{
    constexpr int MT  = WM / 16;
    constexpr int NT  = WN / 16;
    constexpr int RWN = TN / WN;
    __shared__ __align__(16) short As[TM * 72];
    __shared__ __align__(16) short Bs[TN * 72];
    int tid = threadIdx.x;
    int m0 = blockIdx.y * TM, n0 = blockIdx.x * TN;
    int lane = tid & 63, w = tid >> 6;
    int lm = lane & 15, lq = lane >> 4;
    int wm = (w / RWN) * WM, wn = (w % RWN) * WN;
    f4v acc[MT][NT];
#pragma unroll
    for (int i = 0; i < MT; i++)
#pragma unroll
        for (int j = 0; j < NT; j++) acc[i][j] = (f4v){0.f, 0.f, 0.f, 0.f};

    for (int k0 = 0; k0 < K; k0 += 64) {
        for (int c = tid; c < TM * 8; c += 256) {
            int r = c >> 3, kc = (c & 7) << 3;
            *(s8v*)&As[r * 72 + kc] = *(const s8v*)&A[(size_t)(m0 + r) * K + k0 + kc];
        }
        for (int c = tid; c < TN * 8; c += 256) {
            int r = c >> 3, kc = (c & 7) << 3;
            *(s8v*)&Bs[r * 72 + kc] = *(const s8v*)&Bt[(size_t)(n0 + r) * K + k0 + kc];
        }
        __syncthreads();
#pragma unroll
        for (int cc = 0; cc < 2; cc++) {
            s8v af[MT], bfv[NT];
#pragma unroll
            for (int i = 0; i < MT; i++)
                af[i] = *(const s8v*)&As[(wm + i * 16 + lm) * 72 + cc * 32 + lq * 8];
#pragma unroll
            for (int j = 0; j < NT; j++)
                bfv[j] = *(const s8v*)&Bs[(wn + j * 16 + lm) * 72 + cc * 32 + lq * 8];
#pragma unroll
            for (int i = 0; i < MT; i++)
#pragma unroll
                for (int j = 0; j < NT; j++)
                    acc[i][j] = __builtin_amdgcn_mfma_f32_16x16x32_bf16(af[i], bfv[j], acc[i][j], 0, 0, 0);
        }
        __syncthreads();
    }
#pragma unroll
    for (int i = 0; i < MT; i++) {
        int row = m0 + wm + i * 16 + lq * 4;
#pragma unroll
        for (int j = 0; j < NT; j++) {
            int col = n0 + wn + j * 16 + lm;
            float bv = bias ? bias[col] : 0.f;
#pragma unroll
            for (int r = 0; r < 4; r++) {
                float v = acc[i][j][r] + bv;
                if (relu) v = fmaxf(v, 0.f);
                size_t idx = (size_t)(row + r) * ldc + col;
                if (OUTBF) {
                    Cb[idx] = f2b(v);
                } else {
                    if (res) v += res[idx];
                    Cf[idx] = v;
                    if (Cb2) Cb2[(size_t)(row + r) * ldc2 + col] = f2b(v);
                }
            }
        }
    }
}

// ---------------------------------------------------------------------------
// Batched kv GEMM for 4 layers: kvall[z] = [rgbf | hall[base+z]] @ kvpT[base+z]^T
// A: rgbf [BSV][256] + hall [8][BSV][32] (K=288). B: kvpT [8][512][288].
// Tile 128x128, 4 waves of 64x64. grid (4, 256, 4).
// ---------------------------------------------------------------------------
__global__ __launch_bounds__(256) void kvbatch(
    const short* __restrict__ rgbf, const short* __restrict__ hall,
    const short* __restrict__ kvpT, short* __restrict__ kvall, int base)
{
    __shared__ __align__(16) short As[128 * 72];
    __shared__ __align__(16) short Bs[128 * 72];
    int z = blockIdx.z, layer = base + z;
    const short* H  = hall + (size_t)layer * BSV * 32;
    const short* Bt = kvpT + (size_t)layer * 512 * 288;
    short* C = kvall + (size_t)z * BSV * 512;
    int tid = threadIdx.x;
    int m0 = blockIdx.y * 128, n0 = blockIdx.x * 128;
    int lane = tid & 63, w = tid >> 6;
    int lm = lane & 15, lq = lane >> 4;
    int wm = (w >> 1) * 64, wn = (w & 1) * 64;
    f4v acc[4][4];
#pragma unroll
    for (int i = 0; i < 4; i++)
#pragma unroll
        for (int j = 0; j < 4; j++) acc[i][j] = (f4v){0.f, 0.f, 0.f, 0.f};

    for (int k0 = 0; k0 < 256; k0 += 64) {
#pragma unroll
        for (int c = 0; c < 4; c++) {
            int e = tid + c * 256;
            int r = e >> 3, kc = (e & 7) << 3;
            *(s8v*)&As[r * 72 + kc] = *(const s8v*)&rgbf[(size_t)(m0 + r) * 256 + k0 + kc];
            *(s8v*)&Bs[r * 72 + kc] = *(const s8v*)&Bt[(size_t)(n0 + r) * 288 + k0 + kc];
        }
        __syncthreads();
#pragma unroll
        for (int cc = 0; cc < 2; cc++) {
            s8v af[4], bfv[4];
#pragma unroll
            for (int i = 0; i < 4; i++)
                af[i] = *(const s8v*)&As[(wm + i * 16 + lm) * 72 + cc * 32 + lq * 8];
#pragma unroll
            for (int j = 0; j < 4; j++)
                bfv[j] = *(const s8v*)&Bs[(wn + j * 16 + lm) * 72 + cc * 32 + lq * 8];
#pragma unroll
            for (int i = 0; i < 4; i++)
#pragma unroll
                for (int j = 0; j < 4; j++)
                    acc[i][j] = __builtin_amdgcn_mfma_f32_16x16x32_bf16(af[i], bfv[j], acc[i][j], 0, 0, 0);
        }
        __syncthreads();
    }
    // K tail (32, from hall / kvpT cols 256..287)
#pragma unroll
    for (int c = 0; c < 2; c++) {
        int e = tid + c * 256;
        int r = e >> 2, kc = (e & 3) << 3;
        *(s8v*)&As[r * 72 + kc] = *(const s8v*)&H[(size_t)(m0 + r) * 32 + kc];
        *(s8v*)&Bs[r * 72 + kc] = *(const s8v*)&Bt[(size_t)(n0 + r) * 288 + 256 + kc];
    }
    __syncthreads();
    {
        s8v af[4], bfv[4];
#pragma unroll
        for (int i = 0; i < 4; i++)
            af[i] = *(const s8v*)&As[(wm + i * 16 + lm) * 72 + lq * 8];
#pragma unroll
        for (int j = 0; j < 4; j++)
            bfv[j] = *(const s8v*)&Bs[(wn + j * 16 + lm) * 72 + lq * 8];
#pragma unroll
        for (int i = 0; i < 4; i++)
#pragma unroll
            for (int j = 0; j < 4; j++)
                acc[i][j] = __builtin_amdgcn_mfma_f32_16x16x32_bf16(af[i], bfv[j], acc[i][j], 0, 0, 0);
    }
#pragma unroll
    for (int i = 0; i < 4; i++) {
        int row = m0 + wm + i * 16 + lq * 4;
#pragma unroll
        for (int j = 0; j < 4; j++) {
            int col = n0 + wn + j * 16 + lm;
#pragma unroll
            for (int r = 0; r < 4; r++)
                C[(size_t)(row + r) * 512 + col] = f2b(acc[i][j][r]);
        }
    }
}

// hall[l][row][t] = relu(ray_diff[row] @ pw1[l] + pb1[l])  (all 8 layers)
__global__ void hallk(const float* __restrict__ rdiff, const float* __restrict__ pw1,
                      const float* __restrict__ pb1, short* __restrict__ hall)
{
    int idx = blockIdx.x * 256 + threadIdx.x;   // 8*BSV*32 = 2^23
    int t = idx & 31, row = (idx >> 5) & (BSV - 1), l = idx >> 20;
    float a = pb1[l * 32 + t];
    for (int c = 0; c < 4; c++) a += rdiff[row * 4 + c] * pw1[l * 128 + c * 32 + t];
    hall[idx] = f2b(fmaxf(a, 0.f));
}

// ---------------------------------------------------------------------------
// Fused cross-attention: per block = 8 samples (64 kv rows).
// ---------------------------------------------------------------------------
__global__ __launch_bounds__(256) void crossattn(
    const short* __restrict__ kv, const float* __restrict__ qf,
    const int* __restrict__ mask,
    const short* __restrict__ aw1T, const float* __restrict__ ab1,
    const short* __restrict__ aw2T, const float* __restrict__ ab2,
    short* __restrict__ obb)
{
    __shared__ __align__(16) short a_s[64 * 264];   // a_in, later v+pos
    __shared__ __align__(16) short w_s[256 * 40];   // aw1T, then aw2T
    __shared__ __align__(16) short ph_s[64 * 40];
    __shared__ int msk[64];
    int blk = blockIdx.x, tid = threadIdx.x;
    int row0 = blk * 64, bs0 = blk * 8;
    int lane = tid & 63, w = tid >> 6, lm = lane & 15, lq = lane >> 4;
    if (tid < 64) msk[tid] = mask[bs0 * 8 + tid];
#pragma unroll
    for (int i = 0; i < 8; i++) {
        int e = tid + i * 256;
        int r = e >> 5, col = (e & 31) << 3;
        s8v kk = *(const s8v*)&kv[(size_t)(row0 + r) * 512 + col];
        const float* qp = &qf[(size_t)(bs0 + (r >> 3)) * 256 + col];
        s8v o;
#pragma unroll
        for (int j = 0; j < 8; j++) o[j] = f2b(b2f(kk[j]) - qp[j]);
        *(s8v*)&a_s[r * 264 + col] = o;
    }
#pragma unroll
    for (int i = 0; i < 4; i++) {
        int e = tid + i * 256;
        int r = e >> 5, col = (e & 31) << 3;
        *(s8v*)&w_s[r * 264 + col] = *(const s8v*)&aw1T[r * 256 + col];
    }
    __syncthreads();
    f4v a2[2];
    a2[0] = (f4v){0.f, 0.f, 0.f, 0.f}; a2[1] = (f4v){0.f, 0.f, 0.f, 0.f};
#pragma unroll
    for (int c = 0; c < 8; c++) {
        s8v af = *(const s8v*)&a_s[(w * 16 + lm) * 264 + c * 32 + lq * 8];
#pragma unroll
        for (int j = 0; j < 2; j++) {
            s8v bf = *(const s8v*)&w_s[(j * 16 + lm) * 264 + c * 32 + lq * 8];
            a2[j] = __builtin_amdgcn_mfma_f32_16x16x32_bf16(af, bf, a2[j], 0, 0, 0);
        }
    }
#pragma unroll
    for (int j = 0; j < 2; j++) {
        int col = j * 16 + lm;
        float bv = ab1[col];
#pragma unroll
        for (int r = 0; r < 4; r++)
            ph_s[(w * 16 + lq * 4 + r) * 40 + col] = f2b(fmaxf(a2[j][r] + bv, 0.f));
    }
    __syncthreads();
#pragma unroll
    for (int i = 0; i < 4; i++) {
        int e = tid + i * 256;
        int r = e >> 2, col = (e & 3) << 3;
        *(s8v*)&w_s[r * 40 + col] = *(const s8v*)&aw2T[r * 32 + col];
    }
#pragma unroll
    for (int i = 0; i < 8; i++) {
        int e = tid + i * 256;
        int r = e >> 5, col = (e & 31) << 3;
        *(s8v*)&a_s[r * 264 + col] = *(const s8v*)&kv[(size_t)(row0 + r) * 512 + 256 + col];
    }
    __syncthreads();
    s8v pf = *(const s8v*)&ph_s[(w * 16 + lm) * 40 + lq * 8];
    f4v a3[16];
#pragma unroll
    for (int j = 0; j < 16; j++) {
        s8v bf = *(const s8v*)&w_s[(j * 16 + lm) * 40 + lq * 8];
        a3[j] = __builtin_amdgcn_mfma_f32_16x16x32_bf16(pf, bf, (f4v){0.f, 0.f, 0.f, 0.f}, 0, 0, 0);
    }
    int sample = 2 * w + (lq >> 1);
    int mk[4];
#pragma unroll
    for (int r = 0; r < 4; r++) mk[r] = msk[sample * 8 + (lq & 1) * 4 + r];
#pragma unroll
    for (int j = 0; j < 16; j++) {
        int col = j * 16 + lm;
        float bv = ab2[col];
        float vals[4];
#pragma unroll
        for (int r = 0; r < 4; r++) vals[r] = mk[r] ? (a3[j][r] + bv) : -1e9f;
        float mx = fmaxf(fmaxf(vals[0], vals[1]), fmaxf(vals[2], vals[3]));
        mx = fmaxf(mx, __shfl_xor(mx, 16));
        float ev[4], s = 0.f;
#pragma unroll
        for (int r = 0; r < 4; r++) { ev[r] = expf(vals[r] - mx); s += ev[r]; }
        s += __shfl_xor(s, 16);
        float o = 0.f;
#pragma unroll
        for (int r = 0; r < 4; r++)
            o += ev[r] * b2f(a_s[(w * 16 + lq * 4 + r) * 264 + col]);
        o += __shfl_xor(o, 16);
        o /= s;
        if (!(lq & 1)) obb[(size_t)(bs0 + sample) * 256 + col] = f2b(o);
    }
}

// LayerNorm over 256, fp32 in -> bf16 out
__global__ __launch_bounds__(256) void lnormB(
    const float* __restrict__ in, const float* __restrict__ g,
    const float* __restrict__ b, short* __restrict__ out, float eps)
{
    int row = blockIdx.x, t = threadIdx.x;
    float x = in[(size_t)row * WW + t];
    __shared__ float red[256];
    red[t] = x;
    __syncthreads();
    for (int s = 128; s > 0; s >>= 1) { if (t < s) red[t] += red[t + s]; __syncthreads(); }
    float m = red[0] * (1.f / 256.f);
    __syncthreads();
    float d = x - m;
    red[t] = d * d;
    __syncthreads();
    for (int s = 128; s > 0; s >>= 1) { if (t < s) red[t] += red[t + s]; __syncthreads(); }
    float var = red[0] * (1.f / 256.f);
    out[(size_t)row * WW + t] = f2b(d / sqrtf(var + eps) * g[t] + b[t]);
}

// Weight convert+transpose: W fp32 [K,N] -> Wt bf16 [N,Kpad]
__global__ void wconv(const float* __restrict__ W, short* __restrict__ Wt,
                      int K, int N, int Kpad, int zi, size_t zo)
{
    __shared__ float t[32][33];
    int z = blockIdx.z;
    W  += (size_t)z * zi;
    Wt += (size_t)z * zo;
    int n0 = blockIdx.x * 32, k0 = blockIdx.y * 32;
    int tx = threadIdx.x, ty = threadIdx.y;
#pragma unroll
    for (int i = 0; i < 4; i++) {
        int k = k0 + ty + i * 8;
        t[ty + i * 8][tx] = (k < K) ? W[(size_t)k * N + n0 + tx] : 0.f;
    }
    __syncthreads();
#pragma unroll
    for (int i = 0; i < 4; i++) {
        int n = n0 + ty + i * 8;
        Wt[(size_t)n * Kpad + k0 + tx] = f2b(t[tx][ty + i * 8]);
    }
}

// rgb_feat fp32 [32768,35] -> bf16 [32768,64] zero-padded
__global__ void rgbconv(const float* __restrict__ x, short* __restrict__ o)
{
    int idx = blockIdx.x * 256 + threadIdx.x;
    int row = idx >> 6, col = idx & 63;
    o[idx] = f2b(col < 35 ? x[row * 35 + col] : 0.f);
}

__global__ void penc_pts(const float* __restrict__ pts, float* __restrict__ out)
{
    int bs = blockIdx.x * blockDim.x + threadIdx.x;
    if (bs >= BS) return;
    float xs[3] = {pts[bs * 3], pts[bs * 3 + 1], pts[bs * 3 + 2]};
    float* o = out + (size_t)bs * 63;
    o[0] = xs[0]; o[1] = xs[1]; o[2] = xs[2];
    for (int d = 0; d < 3; d++) {
        float f = 1.f;
        for (int k = 0; k < 10; k++) {
            float ang = xs[d] * f;
            o[3 + d * 10 + k]  = sinf(ang);
            o[33 + d * 10 + k] = cosf(ang);
            f *= 2.f;
        }
    }
}

__global__ void penc_views(const float* __restrict__ ray_d, float* __restrict__ out)
{
    int b = threadIdx.x;
    if (b >= BB) return;
    float x = ray_d[b * 3], y = ray_d[b * 3 + 1], z = ray_d[b * 3 + 2];
    float inv = 1.f / sqrtf(x * x + y * y + z * z);
    float v[3] = {x * inv, y * inv, z * inv};
    float* o = out + (size_t)b * 27;
    o[0] = v[0]; o[1] = v[1]; o[2] = v[2];
    for (int d = 0; d < 3; d++) {
        float f = 1.f;
        for (int k = 0; k < 4; k++) {
            float ang = v[d] * f;
            o[3 + d * 4 + k]  = sinf(ang);
            o[15 + d * 4 + k] = cosf(ang);
            f *= 2.f;
        }
    }
}

// static tail of cat buffer: catb[bs][256..383] = [ipts(63) | ivw(27) | 0(38)]
__global__ void catfill(const float* __restrict__ ipts, const float* __restrict__ ivw,
                        short* __restrict__ catb)
{
    int idx = blockIdx.x * 256 + threadIdx.x;   // 4096*128
    int bs = idx >> 7, c = idx & 127;
    float v;
    if (c < 63)      v = ipts[bs * 63 + c];
    else if (c < 90) v = ivw[(bs >> 6) * 27 + (c - 63)];
    else             v = 0.f;
    catb[(size_t)bs * 384 + 256 + c] = f2b(v);
}

// view-max + layer-0 LayerNorm fused: fq fp32 + xq bf16 (rgbf stride 256)
__global__ __launch_bounds__(256) void vmaxln(
    const short* __restrict__ rgbf, const float* __restrict__ g,
    const float* __restrict__ b, float* __restrict__ fq, short* __restrict__ xq)
{
    int bs = blockIdx.x, t = threadIdx.x;
    float m = -1e30f;
    for (int v = 0; v < VV; v++) m = fmaxf(m, b2f(rgbf[((size_t)(bs * VV + v)) * 256 + t]));
    fq[(size_t)bs * WW + t] = m;
    __shared__ float red[256];
    red[t] = m;
    __syncthreads();
    for (int s = 128; s > 0; s >>= 1) { if (t < s) red[t] += red[t + s]; __syncthreads(); }
    float mean = red[0] * (1.f / 256.f);
    __syncthreads();
    float d = m - mean;
    red[t] = d * d;
    __syncthreads();
    for (int s = 128; s > 0; s >>= 1) { if (t < s) red[t] += red[t + s]; __syncthreads(); }
    float var = red[0] * (1.f / 256.f);
    xq[(size_t)bs * WW + t] = f2b(d / sqrtf(var + 1e-6f) * g[t] + b[t]);
}

// ---------------------------------------------------------------------------
// MFMA self-attention: one wave per (b,h). QKV packed bf16 [4096,768].
// ---------------------------------------------------------------------------
__global__ __launch_bounds__(64) void attn_mfma(
    const short* __restrict__ QKV, short* __restrict__ O)
{
    __shared__ __align__(16) short P[64 * 72];
    __shared__ __align__(16) short Vt[64 * 72];
    int blk = blockIdx.x;
    int b = blk >> 2, h = blk & 3, lane = threadIdx.x;
    int lm = lane & 15, lq = lane >> 4;
    const short* base = QKV + (size_t)b * 64 * 768 + h * 64;
    {
        const short* vrow = base + 512 + (size_t)lane * 768;
#pragma unroll
        for (int c = 0; c < 8; c++) {
            s8v v = *(const s8v*)&vrow[c * 8];
#pragma unroll
            for (int j = 0; j < 8; j++)
                Vt[(c * 8 + j) * 72 + lane] = v[j];
        }
    }
    s8v qfr[4][2], kf[4][2];
#pragma unroll
    for (int i = 0; i < 4; i++)
#pragma unroll
        for (int c = 0; c < 2; c++) {
            qfr[i][c] = *(const s8v*)&base[(size_t)(i * 16 + lm) * 768 + c * 32 + lq * 8];
            kf[i][c]  = *(const s8v*)&base[(size_t)(i * 16 + lm) * 768 + 256 + c * 32 + lq * 8];
        }
    f4v acc[4][4];
#pragma unroll
    for (int i = 0; i < 4; i++)
#pragma unroll
        for (int j = 0; j < 4; j++) acc[i][j] = (f4v){0.f, 0.f, 0.f, 0.f};
#pragma unroll
    for (int c = 0; c < 2; c++)
#pragma unroll
        for (int i = 0; i < 4; i++)
#pragma unroll
            for (int j = 0; j < 4; j++)
                acc[i][j] = __builtin_amdgcn_mfma_f32_16x16x32_bf16(qfr[i][c], kf[j][c], acc[i][j], 0, 0, 0);
#pragma unroll
    for (int i = 0; i < 4; i++) {
#pragma unroll
        for (int r = 0; r < 4; r++) {
            float lv[4];
#pragma unroll
            for (int j = 0; j < 4; j++) lv[j] = acc[i][j][r] * 0.125f;
            float mx = fmaxf(fmaxf(lv[0], lv[1]), fmaxf(lv[2], lv[3]));
            for (int d = 1; d < 16; d <<= 1) mx = fmaxf(mx, __shfl_xor(mx, d));
            float sum = 0.f;
#pragma unroll
            for (int j = 0; j < 4; j++) { lv[j] = expf(lv[j] - mx); sum += lv[j]; }
            for (int d = 1; d < 16; d <<= 1) sum += __shfl_xor(sum, d);
            float inv = 1.f / sum;
            int row = i * 16 + lq * 4 + r;
#pragma unroll
            for (int j = 0; j < 4; j++)
                P[row * 72 + j * 16 + lm] = f2b(lv[j] * inv);
        }
    }
    __syncthreads();
    s8v af[4][2], bf[4][2];
#pragma unroll
    for (int i = 0; i < 4; i++)
#pragma unroll
        for (int c = 0; c < 2; c++) {
            af[i][c] = *(const s8v*)&P[(i * 16 + lm) * 72 + c * 32 + lq * 8];
            bf[i][c] = *(const s8v*)&Vt[(i * 16 + lm) * 72 + c * 32 + lq * 8];
        }
    f4v o2[4][4];
#pragma unroll
    for (int i = 0; i < 4; i++)
#pragma unroll
        for (int j = 0; j < 4; j++) o2[i][j] = (f4v){0.f, 0.f, 0.f, 0.f};
#pragma unroll
    for (int c = 0; c < 2; c++)
#pragma unroll
        for (int i = 0; i < 4; i++)
#pragma unroll
            for (int j = 0; j < 4; j++)
                o2[i][j] = __builtin_amdgcn_mfma_f32_16x16x32_bf16(af[i][c], bf[j][c], o2[i][j], 0, 0, 0);
#pragma unroll
    for (int i = 0; i < 4; i++)
#pragma unroll
        for (int j = 0; j < 4; j++)
#pragma unroll
            for (int r = 0; r < 4; r++) {
                int s = i * 16 + lq * 4 + r, d = j * 16 + lm;
                O[(size_t)(b * 64 + s) * 256 + h * 64 + d] = f2b(o2[i][j][r]);
            }
}

// final head: mean over S (bf16 in) then [256]x[256,3] matvec + bias (fp32)
__global__ __launch_bounds__(256) void headk(
    const short* __restrict__ h, const float* __restrict__ ow,
    const float* __restrict__ ob, float* __restrict__ out)
{
    int b = blockIdx.x, t = threadIdx.x;
    float acc = 0.f;
    for (int s = 0; s < SS; s++) acc += b2f(h[((size_t)(b * SS + s)) * WW + t]);
    __shared__ float mean[256];
    mean[t] = acc * (1.f / 64.f);
    __syncthreads();
    if (t < 3) {
        float o = ob[t];
        for (int w = 0; w < WW; w++) o += mean[w] * ow[w * 3 + t];
        out[b * 3 + t] = o;
    }
}

// ---------------------------------------------------------------------------
#define GEMM_BF(TMv,TNv,WMv,WNv, A,Bt,bias,C,M,N,K,ldc,relu) \
  gemm_mfma<TMv,TNv,WMv,WNv,true><<<dim3((N)/(TNv),(M)/(TMv)),256,0,stream>>>((A),(Bt),(bias),nullptr,nullptr,(C),nullptr,(M),(N),(K),(ldc),0,(relu))
#define GEMM_F(TMv,TNv,WMv,WNv, A,Bt,bias,res,C,M,N,K,relu) \
  gemm_mfma<TMv,TNv,WMv,WNv,false><<<dim3((N)/(TNv),(M)/(TMv)),256,0,stream>>>((A),(Bt),(bias),(res),(C),nullptr,nullptr,(M),(N),(K),(N),0,(relu))
#define GEMM_F2(TMv,TNv,WMv,WNv, A,Bt,bias,res,C,C2,ldc2,M,N,K,relu) \
  gemm_mfma<TMv,TNv,WMv,WNv,false><<<dim3((N)/(TNv),(M)/(TMv)),256,0,stream>>>((A),(Bt),(bias),(res),(C),nullptr,(C2),(M),(N),(K),(N),(ldc2),(relu))

extern "C" void kernel_launch(void* const* d_in, const int* in_sizes, int n_in,
                              void* d_out, int out_size, void* d_ws, size_t ws_size,
                              hipStream_t stream)
{
    const float* rgb_feat   = (const float*)d_in[0];
    const float* ray_diff   = (const float*)d_in[1];
    const int*   maskp      = (const int*)d_in[2];
    const float* pts        = (const float*)d_in[3];
    const float* ray_d      = (const float*)d_in[4];
    const float* rgbfeat_w1 = (const float*)d_in[5];
    const float* rgbfeat_b1 = (const float*)d_in[6];
    const float* rgbfeat_w2 = (const float*)d_in[7];
    const float* rgbfeat_b2 = (const float*)d_in[8];
    const float* c_ln_g = (const float*)d_in[9];
    const float* c_ln_b = (const float*)d_in[10];
    const float* c_qw   = (const float*)d_in[11];
    const float* c_kw   = (const float*)d_in[12];
    const float* c_vw   = (const float*)d_in[13];
    const float* c_pw1  = (const float*)d_in[14];
    const float* c_pb1  = (const float*)d_in[15];
    const float* c_pw2  = (const float*)d_in[16];
    const float* c_pb2  = (const float*)d_in[17];
    const float* c_aw1  = (const float*)d_in[18];
    const float* c_ab1  = (const float*)d_in[19];
    const float* c_aw2  = (const float*)d_in[20];
    const float* c_ab2  = (const float*)d_in[21];
    const float* c_ow   = (const float*)d_in[22];
    const float* c_ob   = (const float*)d_in[23];
    const float* c_fg   = (const float*)d_in[24];
    const float* c_fb   = (const float*)d_in[25];
    const float* c_fw1  = (const float*)d_in[26];
    const float* c_fb1  = (const float*)d_in[27];
    const float* c_fw2  = (const float*)d_in[28];
    const float* c_fb2  = (const float*)d_in[29];
    const float* s_ln_g = (const float*)d_in[30];
    const float* s_ln_b = (const float*)d_in[31];
    const float* s_qw   = (const float*)d_in[32];
    const float* s_kw   = (const float*)d_in[33];
    const float* s_vw   = (const float*)d_in[34];
    const float* s_ow   = (const float*)d_in[35];
    const float* s_ob   = (const float*)d_in[36];
    const float* s_fg   = (const float*)d_in[37];
    const float* s_fb   = (const float*)d_in[38];
    const float* s_fw1  = (const float*)d_in[39];
    const float* s_fb1  = (const float*)d_in[40];
    const float* s_fw2  = (const float*)d_in[41];
    const float* s_fb2  = (const float*)d_in[42];
    const float* q_w1   = (const float*)d_in[43];
    const float* q_b1   = (const float*)d_in[44];
    const float* q_w2   = (const float*)d_in[45];
    const float* q_b2   = (const float*)d_in[46];
    const float* norm_g = (const float*)d_in[47];
    const float* norm_b = (const float*)d_in[48];
    const float* out_w  = (const float*)d_in[49];
    const float* out_b  = (const float*)d_in[50];
    float* out = (float*)d_out;

    // ---- workspace carve (256B aligned) ----
    char* p = (char*)d_ws;
    auto alloc = [&](size_t bytes) { char* r = p; p += (bytes + 255) & ~(size_t)255; return r; };
    short* rgbf  = (short*)alloc((size_t)BSV * 256 * 2);       // 16.8 MB
    short* hall  = (short*)alloc((size_t)DD * BSV * 32 * 2);   // 16.8 MB
    short* kvall = (short*)alloc((size_t)4 * BSV * 512 * 2);   // 134 MB
    short* a_in  = (short*)alloc((size_t)BSV * 256 * 2);       // preamble temp
    short* obb   = (short*)alloc((size_t)BS * 256 * 2);
    short* xq    = (short*)alloc((size_t)BS * 256 * 2);
    short* hb    = (short*)alloc((size_t)BS * 256 * 2);
    short* ffh   = (short*)alloc((size_t)BS * 1024 * 2);
    short* catb  = (short*)alloc((size_t)BS * 384 * 2);
    short* qkv   = (short*)alloc((size_t)BS * 768 * 2);        // also rgbp alias
    short* rgbp  = qkv;
    float* qf    = (float*)alloc((size_t)BS * 256 * 4);
    float* fq    = (float*)alloc((size_t)BS * 256 * 4);
    float* ipts  = (float*)alloc((size_t)BS * 63 * 4);
    float* ivw   = (float*)alloc((size_t)BB * 27 * 4);
    // weights (bf16, transposed [N,Kpad])
    short* w1T   = (short*)alloc(256 * 64 * 2);
    short* w2T   = (short*)alloc(256 * 256 * 2);
    short* qwT   = (short*)alloc((size_t)DD * 256 * 256 * 2);
    short* kvpT  = (short*)alloc((size_t)DD * 512 * 288 * 2);
    short* aw1T  = (short*)alloc((size_t)DD * 32 * 256 * 2);
    short* aw2T  = (short*)alloc((size_t)DD * 256 * 32 * 2);
    short* owT   = (short*)alloc((size_t)DD * 256 * 256 * 2);
    short* fw1T  = (short*)alloc((size_t)DD * 1024 * 256 * 2);
    short* fw2T  = (short*)alloc((size_t)DD * 256 * 1024 * 2);
    short* sqkvT = (short*)alloc((size_t)DD * 768 * 256 * 2);
    short* sowT  = (short*)alloc((size_t)DD * 256 * 256 * 2);
    short* sfw1T = (short*)alloc((size_t)DD * 1024 * 256 * 2);
    short* sfw2T = (short*)alloc((size_t)DD * 256 * 1024 * 2);
    short* qw1T  = (short*)alloc((size_t)4 * 256 * 384 * 2);
    short* qw2T  = (short*)alloc((size_t)4 * 256 * 256 * 2);

    // ---- weight conversion ----
    dim3 wb(32, 8);
    wconv<<<dim3(8, 2, 1), wb, 0, stream>>>(rgbfeat_w1, w1T, 35, 256, 64, 0, 0);
    wconv<<<dim3(8, 8, 1), wb, 0, stream>>>(rgbfeat_w2, w2T, 256, 256, 256, 0, 0);
    wconv<<<dim3(8, 8, DD), wb, 0, stream>>>(c_qw, qwT, 256, 256, 256, 65536, 65536);
    wconv<<<dim3(8, 8, DD), wb, 0, stream>>>(c_kw, kvpT, 256, 256, 288, 65536, 147456);
    wconv<<<dim3(8, 1, DD), wb, 0, stream>>>(c_pw2, kvpT + 256, 32, 256, 288, 8192, 147456);
    wconv<<<dim3(8, 8, DD), wb, 0, stream>>>(c_vw, kvpT + 256 * 288, 256, 256, 288, 65536, 147456);
    wconv<<<dim3(8, 1, DD), wb, 0, stream>>>(c_pw2, kvpT + 256 * 288 + 256, 32, 256, 288, 8192, 147456);
    wconv<<<dim3(1, 8, DD), wb, 0, stream>>>(c_aw1, aw1T, 256, 32, 256, 8192, 8192);
    wconv<<<dim3(8, 1, DD), wb, 0, stream>>>(c_aw2, aw2T, 32, 256, 32, 8192, 8192);
    wconv<<<dim3(8, 8, DD), wb, 0, stream>>>(c_ow, owT, 256, 256, 256, 65536, 65536);
    wconv<<<dim3(32, 8, DD), wb, 0, stream>>>(c_fw1, fw1T, 256, 1024, 256, 262144, 262144);
    wconv<<<dim3(8, 32, DD), wb, 0, stream>>>(c_fw2, fw2T, 1024, 256, 1024, 262144, 262144);
    wconv<<<dim3(8, 8, DD), wb, 0, stream>>>(s_qw, sqkvT, 256, 256, 256, 65536, 196608);
    wconv<<<dim3(8, 8, DD), wb, 0, stream>>>(s_kw, sqkvT + 65536, 256, 256, 256, 65536, 196608);
    wconv<<<dim3(8, 8, DD), wb, 0, stream>>>(s_vw, sqkvT + 131072, 256, 256, 256, 65536, 196608);
    wconv<<<dim3(8, 8, DD), wb, 0, stream>>>(s_ow, sowT, 256, 256, 256, 65536, 65536);
    wconv<<<dim3(32, 8, DD), wb, 0, stream>>>(s_fw1, sfw1T, 256, 1024, 256, 262144, 262144);
    wconv<<<dim3(8, 32, DD), wb, 0, stream>>>(s_fw2, sfw2T, 1024, 256, 1024, 262144, 262144);
    wconv<<<dim3(8, 12, 4), wb, 0, stream>>>(q_w1, qw1T, 346, 256, 384, 88576, 98304);
    wconv<<<dim3(8, 8, 4), wb, 0, stream>>>(q_w2, qw2T, 256, 256, 256, 65536, 65536);

    // ---- preamble ----
    penc_pts<<<(BS + 255) / 256, 256, 0, stream>>>(pts, ipts);
    penc_views<<<1, 64, 0, stream>>>(ray_d, ivw);
    catfill<<<(BS * 128) / 256, 256, 0, stream>>>(ipts, ivw, catb);
    rgbconv<<<(BSV * 64) / 256, 256, 0, stream>>>(rgb_feat, rgbp);
    hallk<<<(DD * BSV * 32) / 256, 256, 0, stream>>>(ray_diff, c_pw1, c_pb1, hall);
    GEMM_BF(128, 128, 64, 64, rgbp, w1T, rgbfeat_b1, a_in, BSV, 256, 64, 256, 1);
    GEMM_BF(128, 128, 64, 64, a_in, w2T, rgbfeat_b2, rgbf, BSV, 256, 256, 256, 0);
    vmaxln<<<BS, 256, 0, stream>>>(rgbf, c_ln_g, c_ln_b, fq, xq);
    // kv for layers 0-3 (layers 4-7 launched after layer 3 consumes slot 3)
    kvbatch<<<dim3(4, 256, 4), 256, 0, stream>>>(rgbf, hall, kvpT, kvall, 0);

    for (int i = 0; i < DD; i++) {
        int j = i >> 1;
        if (i == 4)
            kvbatch<<<dim3(4, 256, 4), 256, 0, stream>>>(rgbf, hall, kvpT, kvall, 4);
        // ---- cross transformer ----
        if (i > 0)
            lnormB<<<BS, 256, 0, stream>>>(fq, c_ln_g + i * WW, c_ln_b + i * WW, xq, 1e-6f);
        GEMM_F(64, 64, 32, 32, xq, qwT + (size_t)i * 65536, nullptr, nullptr, qf, BS, 256, 256, 0);
        crossattn<<<BSV / 64, 256, 0, stream>>>(kvall + (size_t)(i & 3) * BSV * 512, qf, maskp,
            aw1T + (size_t)i * 8192, c_ab1 + i * 32,
            aw2T + (size_t)i * 8192, c_ab2 + i * 256, obb);
        GEMM_F(64, 64, 32, 32, obb, owT + (size_t)i * 65536, c_ob + i * 256, fq, fq, BS, 256, 256, 0);
        lnormB<<<BS, 256, 0, stream>>>(fq, c_fg + i * WW, c_fb + i * WW, hb, 1e-6f);
        GEMM_BF(64, 128, 32, 64, hb, fw1T + (size_t)i * 262144, c_fb1 + i * 1024, ffh, BS, 1024, 256, 1024, 1);
        if ((i & 1) == 0) {
            // fw2 + residual -> fq, dual bf16 write into catb[:,0..255]
            GEMM_F2(64, 64, 32, 32, ffh, fw2T + (size_t)i * 262144, c_fb2 + i * 256, fq, fq,
                    catb, 384, BS, 256, 1024, 0);
            GEMM_BF(64, 64, 32, 32, catb, qw1T + (size_t)j * 98304, q_b1 + j * 256, hb, BS, 256, 384, 256, 1);
            GEMM_F(64, 64, 32, 32, hb, qw2T + (size_t)j * 65536, q_b2 + j * 256, nullptr, fq, BS, 256, 256, 0);
        } else {
            GEMM_F(64, 64, 32, 32, ffh, fw2T + (size_t)i * 262144, c_fb2 + i * 256, fq, fq, BS, 256, 1024, 0);
        }
        // ---- self transformer ----
        lnormB<<<BS, 256, 0, stream>>>(fq, s_ln_g + i * WW, s_ln_b + i * WW, xq, 1e-6f);
        GEMM_BF(64, 128, 32, 64, xq, sqkvT + (size_t)i * 196608, nullptr, qkv, BS, 768, 256, 768, 0);
        attn_mfma<<<BB * 4, 64, 0, stream>>>(qkv, obb);
        GEMM_F(64, 64, 32, 32, obb, sowT + (size_t)i * 65536, s_ob + i * 256, fq, fq, BS, 256, 256, 0);
        lnormB<<<BS, 256, 0, stream>>>(fq, s_fg + i * WW, s_fb + i * WW, hb, 1e-6f);
        GEMM_BF(64, 128, 32, 64, hb, sfw1T + (size_t)i * 262144, s_fb1 + i * 1024, ffh, BS, 1024, 256, 1024, 1);
        GEMM_F(64, 64, 32, 32, ffh, sfw2T + (size_t)i * 262144, s_fb2 + i * 256, fq, fq, BS, 256, 1024, 0);
    }

    // ---- final norm + head ----
    lnormB<<<BS, 256, 0, stream>>>(fq, norm_g, norm_b, hb, 1e-5f);
    headk<<<BB, 256, 0, stream>>>(hb, out_w, out_b, out);
}

// Round 7
// 1777.907 us; speedup vs baseline: 1.1896x; 1.1896x over previous
//
#include <hip/hip_runtime.h>
#include <hip/hip_bf16.h>
#include <math.h>

#define BB 64
#define SS 64
#define VV 8
#define WW 256
#define DD 8
#define BS (BB*SS)        // 4096
#define BSV (BB*SS*VV)    // 32768

typedef __attribute__((ext_vector_type(8))) short s8v;
typedef __attribute__((ext_vector_type(4))) float f4v;

__device__ __forceinline__ short f2b(float f) {
    __hip_bfloat16 h = __float2bfloat16(f);
    return *reinterpret_cast<short*>(&h);
}
__device__ __forceinline__ float b2f(short s) {
    __hip_bfloat16 h = *reinterpret_cast<__hip_bfloat16*>(&s);
    return __bfloat162float(h);
}

// ---------------------------------------------------------------------------
// bf16 MFMA GEMM (R4 config: BK=32, LDS stride 40): C = act(A@B + bias) (+res)
// A bf16 [M,K]. Bt bf16 [N,K]. Dual output: Cf fp32 (ldc) and optional
// Cb2 bf16 (ldc2); or single bf16 Cb when OUTBF.
// ---------------------------------------------------------------------------
template<int TM, int TN, int WM, int WN, bool OUTBF>
__global__ __launch_bounds__(256) void gemm_mfma(
    const short* __restrict__ A, const short* __restrict__ Bt,
    const float* __restrict__ bias, const float* __restrict__ res,
    float* __restrict__ Cf, short* __restrict__ Cb, short* __restrict__ Cb2,
    int M, int N, int K, int ldc, int ldc2, int relu)
{
    constexpr int MT  = WM / 16;
    constexpr int NT  = WN / 16;
    constexpr int RWN = TN / WN;
    __shared__ __align__(16) short As[TM * 40];
    __shared__ __align__(16) short Bs[TN * 40];
    int tid = threadIdx.x;
    int m0 = blockIdx.y * TM, n0 = blockIdx.x * TN;
    int lane = tid & 63, w = tid >> 6;
    int lm = lane & 15, lq = lane >> 4;
    int wm = (w / RWN) * WM, wn = (w % RWN) * WN;
    f4v acc[MT][NT];
#pragma unroll
    for (int i = 0; i < MT; i++)
#pragma unroll
        for (int j = 0; j < NT; j++) acc[i][j] = (f4v){0.f, 0.f, 0.f, 0.f};

    for (int k0 = 0; k0 < K; k0 += 32) {
        for (int c = tid; c < TM * 4; c += 256) {
            int r = c >> 2, kc = (c & 3) << 3;
            *(s8v*)&As[r * 40 + kc] = *(const s8v*)&A[(size_t)(m0 + r) * K + k0 + kc];
        }
        for (int c = tid; c < TN * 4; c += 256) {
            int r = c >> 2, kc = (c & 3) << 3;
            *(s8v*)&Bs[r * 40 + kc] = *(const s8v*)&Bt[(size_t)(n0 + r) * K + k0 + kc];
        }
        __syncthreads();
        s8v af[MT], bfv[NT];
#pragma unroll
        for (int i = 0; i < MT; i++)
            af[i] = *(const s8v*)&As[(wm + i * 16 + lm) * 40 + lq * 8];
#pragma unroll
        for (int j = 0; j < NT; j++)
            bfv[j] = *(const s8v*)&Bs[(wn + j * 16 + lm) * 40 + lq * 8];
#pragma unroll
        for (int i = 0; i < MT; i++)
#pragma unroll
            for (int j = 0; j < NT; j++)
                acc[i][j] = __builtin_amdgcn_mfma_f32_16x16x32_bf16(af[i], bfv[j], acc[i][j], 0, 0, 0);
        __syncthreads();
    }
#pragma unroll
    for (int i = 0; i < MT; i++) {
        int row = m0 + wm + i * 16 + lq * 4;
#pragma unroll
        for (int j = 0; j < NT; j++) {
            int col = n0 + wn + j * 16 + lm;
            float bv = bias ? bias[col] : 0.f;
#pragma unroll
            for (int r = 0; r < 4; r++) {
                float v = acc[i][j][r] + bv;
                if (relu) v = fmaxf(v, 0.f);
                size_t idx = (size_t)(row + r) * ldc + col;
                if (OUTBF) {
                    Cb[idx] = f2b(v);
                } else {
                    if (res) v += res[idx];
                    Cf[idx] = v;
                    if (Cb2) Cb2[(size_t)(row + r) * ldc2 + col] = f2b(v);
                }
            }
        }
    }
}

// ---------------------------------------------------------------------------
// Batched kv GEMM for 4 layers: kvall[z] = [rgbf | hall[base+z]] @ kvpT[base+z]^T
// grid (n=4, z=4, m=256): all 16 blocks sharing an rgbf A-tile are adjacent
// in dispatch order -> L2/LLC serves A once. BK=64, LDS stride 72.
// ---------------------------------------------------------------------------
__global__ __launch_bounds__(256) void kvbatch(
    const short* __restrict__ rgbf, const short* __restrict__ hall,
    const short* __restrict__ kvpT, short* __restrict__ kvall, int base)
{
    __shared__ __align__(16) short As[128 * 72];
    __shared__ __align__(16) short Bs[128 * 72];
    int z = blockIdx.y, layer = base + z;
    const short* H  = hall + (size_t)layer * BSV * 32;
    const short* Bt = kvpT + (size_t)layer * 512 * 288;
    short* C = kvall + (size_t)z * BSV * 512;
    int tid = threadIdx.x;
    int m0 = blockIdx.z * 128, n0 = blockIdx.x * 128;
    int lane = tid & 63, w = tid >> 6;
    int lm = lane & 15, lq = lane >> 4;
    int wm = (w >> 1) * 64, wn = (w & 1) * 64;
    f4v acc[4][4];
#pragma unroll
    for (int i = 0; i < 4; i++)
#pragma unroll
        for (int j = 0; j < 4; j++) acc[i][j] = (f4v){0.f, 0.f, 0.f, 0.f};

    for (int k0 = 0; k0 < 256; k0 += 64) {
#pragma unroll
        for (int c = 0; c < 4; c++) {
            int e = tid + c * 256;
            int r = e >> 3, kc = (e & 7) << 3;
            *(s8v*)&As[r * 72 + kc] = *(const s8v*)&rgbf[(size_t)(m0 + r) * 256 + k0 + kc];
            *(s8v*)&Bs[r * 72 + kc] = *(const s8v*)&Bt[(size_t)(n0 + r) * 288 + k0 + kc];
        }
        __syncthreads();
#pragma unroll
        for (int cc = 0; cc < 2; cc++) {
            s8v af[4], bfv[4];
#pragma unroll
            for (int i = 0; i < 4; i++)
                af[i] = *(const s8v*)&As[(wm + i * 16 + lm) * 72 + cc * 32 + lq * 8];
#pragma unroll
            for (int j = 0; j < 4; j++)
                bfv[j] = *(const s8v*)&Bs[(wn + j * 16 + lm) * 72 + cc * 32 + lq * 8];
#pragma unroll
            for (int i = 0; i < 4; i++)
#pragma unroll
                for (int j = 0; j < 4; j++)
                    acc[i][j] = __builtin_amdgcn_mfma_f32_16x16x32_bf16(af[i], bfv[j], acc[i][j], 0, 0, 0);
        }
        __syncthreads();
    }
    // K tail (32): hall cols / kvpT cols 256..287
#pragma unroll
    for (int c = 0; c < 2; c++) {
        int e = tid + c * 256;
        int r = e >> 2, kc = (e & 3) << 3;
        *(s8v*)&As[r * 72 + kc] = *(const s8v*)&H[(size_t)(m0 + r) * 32 + kc];
        *(s8v*)&Bs[r * 72 + kc] = *(const s8v*)&Bt[(size_t)(n0 + r) * 288 + 256 + kc];
    }
    __syncthreads();
    {
        s8v af[4], bfv[4];
#pragma unroll
        for (int i = 0; i < 4; i++)
            af[i] = *(const s8v*)&As[(wm + i * 16 + lm) * 72 + lq * 8];
#pragma unroll
        for (int j = 0; j < 4; j++)
            bfv[j] = *(const s8v*)&Bs[(wn + j * 16 + lm) * 72 + lq * 8];
#pragma unroll
        for (int i = 0; i < 4; i++)
#pragma unroll
            for (int j = 0; j < 4; j++)
                acc[i][j] = __builtin_amdgcn_mfma_f32_16x16x32_bf16(af[i], bfv[j], acc[i][j], 0, 0, 0);
    }
#pragma unroll
    for (int i = 0; i < 4; i++) {
        int row = m0 + wm + i * 16 + lq * 4;
#pragma unroll
        for (int j = 0; j < 4; j++) {
            int col = n0 + wn + j * 16 + lm;
#pragma unroll
            for (int r = 0; r < 4; r++)
                C[(size_t)(row + r) * 512 + col] = f2b(acc[i][j][r]);
        }
    }
}

// hall[l][row][t] = relu(ray_diff[row] @ pw1[l] + pb1[l])  (all 8 layers)
__global__ void hallk(const float* __restrict__ rdiff, const float* __restrict__ pw1,
                      const float* __restrict__ pb1, short* __restrict__ hall)
{
    int idx = blockIdx.x * 256 + threadIdx.x;   // 8*BSV*32
    int t = idx & 31, row = (idx >> 5) & (BSV - 1), l = idx >> 20;
    float a = pb1[l * 32 + t];
    for (int c = 0; c < 4; c++) a += rdiff[row * 4 + c] * pw1[l * 128 + c * 32 + t];
    hall[idx] = f2b(fmaxf(a, 0.f));
}

// ---------------------------------------------------------------------------
// Fused cross-attention: per block = 8 samples (64 kv rows).
// ---------------------------------------------------------------------------
__global__ __launch_bounds__(256) void crossattn(
    const short* __restrict__ kv, const float* __restrict__ qf,
    const int* __restrict__ mask,
    const short* __restrict__ aw1T, const float* __restrict__ ab1,
    const short* __restrict__ aw2T, const float* __restrict__ ab2,
    short* __restrict__ obb)
{
    __shared__ __align__(16) short a_s[64 * 264];   // a_in, later v+pos
    __shared__ __align__(16) short w_s[256 * 40];   // aw1T, then aw2T
    __shared__ __align__(16) short ph_s[64 * 40];
    __shared__ int msk[64];
    int blk = blockIdx.x, tid = threadIdx.x;
    int row0 = blk * 64, bs0 = blk * 8;
    int lane = tid & 63, w = tid >> 6, lm = lane & 15, lq = lane >> 4;
    if (tid < 64) msk[tid] = mask[bs0 * 8 + tid];
#pragma unroll
    for (int i = 0; i < 8; i++) {
        int e = tid + i * 256;
        int r = e >> 5, col = (e & 31) << 3;
        s8v kk = *(const s8v*)&kv[(size_t)(row0 + r) * 512 + col];
        const float* qp = &qf[(size_t)(bs0 + (r >> 3)) * 256 + col];
        s8v o;
#pragma unroll
        for (int j = 0; j < 8; j++) o[j] = f2b(b2f(kk[j]) - qp[j]);
        *(s8v*)&a_s[r * 264 + col] = o;
    }
#pragma unroll
    for (int i = 0; i < 4; i++) {
        int e = tid + i * 256;
        int r = e >> 5, col = (e & 31) << 3;
        *(s8v*)&w_s[r * 264 + col] = *(const s8v*)&aw1T[r * 256 + col];
    }
    __syncthreads();
    f4v a2[2];
    a2[0] = (f4v){0.f, 0.f, 0.f, 0.f}; a2[1] = (f4v){0.f, 0.f, 0.f, 0.f};
#pragma unroll
    for (int c = 0; c < 8; c++) {
        s8v af = *(const s8v*)&a_s[(w * 16 + lm) * 264 + c * 32 + lq * 8];
#pragma unroll
        for (int j = 0; j < 2; j++) {
            s8v bf = *(const s8v*)&w_s[(j * 16 + lm) * 264 + c * 32 + lq * 8];
            a2[j] = __builtin_amdgcn_mfma_f32_16x16x32_bf16(af, bf, a2[j], 0, 0, 0);
        }
    }
#pragma unroll
    for (int j = 0; j < 2; j++) {
        int col = j * 16 + lm;
        float bv = ab1[col];
#pragma unroll
        for (int r = 0; r < 4; r++)
            ph_s[(w * 16 + lq * 4 + r) * 40 + col] = f2b(fmaxf(a2[j][r] + bv, 0.f));
    }
    __syncthreads();
#pragma unroll
    for (int i = 0; i < 4; i++) {
        int e = tid + i * 256;
        int r = e >> 2, col = (e & 3) << 3;
        *(s8v*)&w_s[r * 40 + col] = *(const s8v*)&aw2T[r * 32 + col];
    }
#pragma unroll
    for (int i = 0; i < 8; i++) {
        int e = tid + i * 256;
        int r = e >> 5, col = (e & 31) << 3;
        *(s8v*)&a_s[r * 264 + col] = *(const s8v*)&kv[(size_t)(row0 + r) * 512 + 256 + col];
    }
    __syncthreads();
    s8v pf = *(const s8v*)&ph_s[(w * 16 + lm) * 40 + lq * 8];
    f4v a3[16];
#pragma unroll
    for (int j = 0; j < 16; j++) {
        s8v bf = *(const s8v*)&w_s[(j * 16 + lm) * 40 + lq * 8];
        a3[j] = __builtin_amdgcn_mfma_f32_16x16x32_bf16(pf, bf, (f4v){0.f, 0.f, 0.f, 0.f}, 0, 0, 0);
    }
    int sample = 2 * w + (lq >> 1);
    int mk[4];
#pragma unroll
    for (int r = 0; r < 4; r++) mk[r] = msk[sample * 8 + (lq & 1) * 4 + r];
#pragma unroll
    for (int j = 0; j < 16; j++) {
        int col = j * 16 + lm;
        float bv = ab2[col];
        float vals[4];
#pragma unroll
        for (int r = 0; r < 4; r++) vals[r] = mk[r] ? (a3[j][r] + bv) : -1e9f;
        float mx = fmaxf(fmaxf(vals[0], vals[1]), fmaxf(vals[2], vals[3]));
        mx = fmaxf(mx, __shfl_xor(mx, 16));
        float ev[4], s = 0.f;
#pragma unroll
        for (int r = 0; r < 4; r++) { ev[r] = expf(vals[r] - mx); s += ev[r]; }
        s += __shfl_xor(s, 16);
        float o = 0.f;
#pragma unroll
        for (int r = 0; r < 4; r++)
            o += ev[r] * b2f(a_s[(w * 16 + lq * 4 + r) * 264 + col]);
        o += __shfl_xor(o, 16);
        o /= s;
        if (!(lq & 1)) obb[(size_t)(bs0 + sample) * 256 + col] = f2b(o);
    }
}

// LayerNorm over 256, fp32 in -> bf16 out
__global__ __launch_bounds__(256) void lnormB(
    const float* __restrict__ in, const float* __restrict__ g,
    const float* __restrict__ b, short* __restrict__ out, float eps)
{
    int row = blockIdx.x, t = threadIdx.x;
    float x = in[(size_t)row * WW + t];
    __shared__ float red[256];
    red[t] = x;
    __syncthreads();
    for (int s = 128; s > 0; s >>= 1) { if (t < s) red[t] += red[t + s]; __syncthreads(); }
    float m = red[0] * (1.f / 256.f);
    __syncthreads();
    float d = x - m;
    red[t] = d * d;
    __syncthreads();
    for (int s = 128; s > 0; s >>= 1) { if (t < s) red[t] += red[t + s]; __syncthreads(); }
    float var = red[0] * (1.f / 256.f);
    out[(size_t)row * WW + t] = f2b(d / sqrtf(var + eps) * g[t] + b[t]);
}

// Weight convert+transpose: W fp32 [K,N] -> Wt bf16 [N,Kpad]
__global__ void wconv(const float* __restrict__ W, short* __restrict__ Wt,
                      int K, int N, int Kpad, int zi, size_t zo)
{
    __shared__ float t[32][33];
    int z = blockIdx.z;
    W  += (size_t)z * zi;
    Wt += (size_t)z * zo;
    int n0 = blockIdx.x * 32, k0 = blockIdx.y * 32;
    int tx = threadIdx.x, ty = threadIdx.y;
#pragma unroll
    for (int i = 0; i < 4; i++) {
        int k = k0 + ty + i * 8;
        t[ty + i * 8][tx] = (k < K) ? W[(size_t)k * N + n0 + tx] : 0.f;
    }
    __syncthreads();
#pragma unroll
    for (int i = 0; i < 4; i++) {
        int n = n0 + ty + i * 8;
        Wt[(size_t)n * Kpad + k0 + tx] = f2b(t[tx][ty + i * 8]);
    }
}

// rgb_feat fp32 [32768,35] -> bf16 [32768,64] zero-padded
__global__ void rgbconv(const float* __restrict__ x, short* __restrict__ o)
{
    int idx = blockIdx.x * 256 + threadIdx.x;
    int row = idx >> 6, col = idx & 63;
    o[idx] = f2b(col < 35 ? x[row * 35 + col] : 0.f);
}

__global__ void penc_pts(const float* __restrict__ pts, float* __restrict__ out)
{
    int bs = blockIdx.x * blockDim.x + threadIdx.x;
    if (bs >= BS) return;
    float xs[3] = {pts[bs * 3], pts[bs * 3 + 1], pts[bs * 3 + 2]};
    float* o = out + (size_t)bs * 63;
    o[0] = xs[0]; o[1] = xs[1]; o[2] = xs[2];
    for (int d = 0; d < 3; d++) {
        float f = 1.f;
        for (int k = 0; k < 10; k++) {
            float ang = xs[d] * f;
            o[3 + d * 10 + k]  = sinf(ang);
            o[33 + d * 10 + k] = cosf(ang);
            f *= 2.f;
        }
    }
}

__global__ void penc_views(const float* __restrict__ ray_d, float* __restrict__ out)
{
    int b = threadIdx.x;
    if (b >= BB) return;
    float x = ray_d[b * 3], y = ray_d[b * 3 + 1], z = ray_d[b * 3 + 2];
    float inv = 1.f / sqrtf(x * x + y * y + z * z);
    float v[3] = {x * inv, y * inv, z * inv};
    float* o = out + (size_t)b * 27;
    o[0] = v[0]; o[1] = v[1]; o[2] = v[2];
    for (int d = 0; d < 3; d++) {
        float f = 1.f;
        for (int k = 0; k < 4; k++) {
            float ang = v[d] * f;
            o[3 + d * 4 + k]  = sinf(ang);
            o[15 + d * 4 + k] = cosf(ang);
            f *= 2.f;
        }
    }
}

// static tail of cat buffer: catb[bs][256..383] = [ipts(63) | ivw(27) | 0(38)]
__global__ void catfill(const float* __restrict__ ipts, const float* __restrict__ ivw,
                        short* __restrict__ catb)
{
    int idx = blockIdx.x * 256 + threadIdx.x;   // 4096*128
    int bs = idx >> 7, c = idx & 127;
    float v;
    if (c < 63)      v = ipts[bs * 63 + c];
    else if (c < 90) v = ivw[(bs >> 6) * 27 + (c - 63)];
    else             v = 0.f;
    catb[(size_t)bs * 384 + 256 + c] = f2b(v);
}

// view-max + layer-0 LayerNorm fused
__global__ __launch_bounds__(256) void vmaxln(
    const short* __restrict__ rgbf, const float* __restrict__ g,
    const float* __restrict__ b, float* __restrict__ fq, short* __restrict__ xq)
{
    int bs = blockIdx.x, t = threadIdx.x;
    float m = -1e30f;
    for (int v = 0; v < VV; v++) m = fmaxf(m, b2f(rgbf[((size_t)(bs * VV + v)) * 256 + t]));
    fq[(size_t)bs * WW + t] = m;
    __shared__ float red[256];
    red[t] = m;
    __syncthreads();
    for (int s = 128; s > 0; s >>= 1) { if (t < s) red[t] += red[t + s]; __syncthreads(); }
    float mean = red[0] * (1.f / 256.f);
    __syncthreads();
    float d = m - mean;
    red[t] = d * d;
    __syncthreads();
    for (int s = 128; s > 0; s >>= 1) { if (t < s) red[t] += red[t + s]; __syncthreads(); }
    float var = red[0] * (1.f / 256.f);
    xq[(size_t)bs * WW + t] = f2b(d / sqrtf(var + 1e-6f) * g[t] + b[t]);
}

// ---------------------------------------------------------------------------
// MFMA self-attention: one wave per (b,h). QKV packed bf16 [4096,768].
// ---------------------------------------------------------------------------
__global__ __launch_bounds__(64) void attn_mfma(
    const short* __restrict__ QKV, short* __restrict__ O)
{
    __shared__ __align__(16) short P[64 * 72];
    __shared__ __align__(16) short Vt[64 * 72];
    int blk = blockIdx.x;
    int b = blk >> 2, h = blk & 3, lane = threadIdx.x;
    int lm = lane & 15, lq = lane >> 4;
    const short* base = QKV + (size_t)b * 64 * 768 + h * 64;
    {
        const short* vrow = base + 512 + (size_t)lane * 768;
#pragma unroll
        for (int c = 0; c < 8; c++) {
            s8v v = *(const s8v*)&vrow[c * 8];
#pragma unroll
            for (int j = 0; j < 8; j++)
                Vt[(c * 8 + j) * 72 + lane] = v[j];
        }
    }
    s8v qfr[4][2], kf[4][2];
#pragma unroll
    for (int i = 0; i < 4; i++)
#pragma unroll
        for (int c = 0; c < 2; c++) {
            qfr[i][c] = *(const s8v*)&base[(size_t)(i * 16 + lm) * 768 + c * 32 + lq * 8];
            kf[i][c]  = *(const s8v*)&base[(size_t)(i * 16 + lm) * 768 + 256 + c * 32 + lq * 8];
        }
    f4v acc[4][4];
#pragma unroll
    for (int i = 0; i < 4; i++)
#pragma unroll
        for (int j = 0; j < 4; j++) acc[i][j] = (f4v){0.f, 0.f, 0.f, 0.f};
#pragma unroll
    for (int c = 0; c < 2; c++)
#pragma unroll
        for (int i = 0; i < 4; i++)
#pragma unroll
            for (int j = 0; j < 4; j++)
                acc[i][j] = __builtin_amdgcn_mfma_f32_16x16x32_bf16(qfr[i][c], kf[j][c], acc[i][j], 0, 0, 0);
#pragma unroll
    for (int i = 0; i < 4; i++) {
#pragma unroll
        for (int r = 0; r < 4; r++) {
            float lv[4];
#pragma unroll
            for (int j = 0; j < 4; j++) lv[j] = acc[i][j][r] * 0.125f;
            float mx = fmaxf(fmaxf(lv[0], lv[1]), fmaxf(lv[2], lv[3]));
            for (int d = 1; d < 16; d <<= 1) mx = fmaxf(mx, __shfl_xor(mx, d));
            float sum = 0.f;
#pragma unroll
            for (int j = 0; j < 4; j++) { lv[j] = expf(lv[j] - mx); sum += lv[j]; }
            for (int d = 1; d < 16; d <<= 1) sum += __shfl_xor(sum, d);
            float inv = 1.f / sum;
            int row = i * 16 + lq * 4 + r;
#pragma unroll
            for (int j = 0; j < 4; j++)
                P[row * 72 + j * 16 + lm] = f2b(lv[j] * inv);
        }
    }
    __syncthreads();
    s8v af[4][2], bf[4][2];
#pragma unroll
    for (int i = 0; i < 4; i++)
#pragma unroll
        for (int c = 0; c < 2; c++) {
            af[i][c] = *(const s8v*)&P[(i * 16 + lm) * 72 + c * 32 + lq * 8];
            bf[i][c] = *(const s8v*)&Vt[(i * 16 + lm) * 72 + c * 32 + lq * 8];
        }
    f4v o2[4][4];
#pragma unroll
    for (int i = 0; i < 4; i++)
#pragma unroll
        for (int j = 0; j < 4; j++) o2[i][j] = (f4v){0.f, 0.f, 0.f, 0.f};
#pragma unroll
    for (int c = 0; c < 2; c++)
#pragma unroll
        for (int i = 0; i < 4; i++)
#pragma unroll
            for (int j = 0; j < 4; j++)
                o2[i][j] = __builtin_amdgcn_mfma_f32_16x16x32_bf16(af[i][c], bf[j][c], o2[i][j], 0, 0, 0);
#pragma unroll
    for (int i = 0; i < 4; i++)
#pragma unroll
        for (int j = 0; j < 4; j++)
#pragma unroll
            for (int r = 0; r < 4; r++) {
                int s = i * 16 + lq * 4 + r, d = j * 16 + lm;
                O[(size_t)(b * 64 + s) * 256 + h * 64 + d] = f2b(o2[i][j][r]);
            }
}

// final head: mean over S (bf16 in) then [256]x[256,3] matvec + bias (fp32)
__global__ __launch_bounds__(256) void headk(
    const short* __restrict__ h, const float* __restrict__ ow,
    const float* __restrict__ ob, float* __restrict__ out)
{
    int b = blockIdx.x, t = threadIdx.x;
    float acc = 0.f;
    for (int s = 0; s < SS; s++) acc += b2f(h[((size_t)(b * SS + s)) * WW + t]);
    __shared__ float mean[256];
    mean[t] = acc * (1.f / 64.f);
    __syncthreads();
    if (t < 3) {
        float o = ob[t];
        for (int w = 0; w < WW; w++) o += mean[w] * ow[w * 3 + t];
        out[b * 3 + t] = o;
    }
}

// ---------------------------------------------------------------------------
#define GEMM_BF(TMv,TNv,WMv,WNv, A,Bt,bias,C,M,N,K,ldc,relu) \
  gemm_mfma<TMv,TNv,WMv,WNv,true><<<dim3((N)/(TNv),(M)/(TMv)),256,0,stream>>>((A),(Bt),(bias),nullptr,nullptr,(C),nullptr,(M),(N),(K),(ldc),0,(relu))
#define GEMM_F(TMv,TNv,WMv,WNv, A,Bt,bias,res,C,M,N,K,relu) \
  gemm_mfma<TMv,TNv,WMv,WNv,false><<<dim3((N)/(TNv),(M)/(TMv)),256,0,stream>>>((A),(Bt),(bias),(res),(C),nullptr,nullptr,(M),(N),(K),(N),0,(relu))
#define GEMM_F2(TMv,TNv,WMv,WNv, A,Bt,bias,res,C,C2,ldc2,M,N,K,relu) \
  gemm_mfma<TMv,TNv,WMv,WNv,false><<<dim3((N)/(TNv),(M)/(TMv)),256,0,stream>>>((A),(Bt),(bias),(res),(C),nullptr,(C2),(M),(N),(K),(N),(ldc2),(relu))

extern "C" void kernel_launch(void* const* d_in, const int* in_sizes, int n_in,
                              void* d_out, int out_size, void* d_ws, size_t ws_size,
                              hipStream_t stream)
{
    const float* rgb_feat   = (const float*)d_in[0];
    const float* ray_diff   = (const float*)d_in[1];
    const int*   maskp      = (const int*)d_in[2];
    const float* pts        = (const float*)d_in[3];
    const float* ray_d      = (const float*)d_in[4];
    const float* rgbfeat_w1 = (const float*)d_in[5];
    const float* rgbfeat_b1 = (const float*)d_in[6];
    const float* rgbfeat_w2 = (const float*)d_in[7];
    const float* rgbfeat_b2 = (const float*)d_in[8];
    const float* c_ln_g = (const float*)d_in[9];
    const float* c_ln_b = (const float*)d_in[10];
    const float* c_qw   = (const float*)d_in[11];
    const float* c_kw   = (const float*)d_in[12];
    const float* c_vw   = (const float*)d_in[13];
    const float* c_pw1  = (const float*)d_in[14];
    const float* c_pb1  = (const float*)d_in[15];
    const float* c_pw2  = (const float*)d_in[16];
    const float* c_pb2  = (const float*)d_in[17];
    const float* c_aw1  = (const float*)d_in[18];
    const float* c_ab1  = (const float*)d_in[19];
    const float* c_aw2  = (const float*)d_in[20];
    const float* c_ab2  = (const float*)d_in[21];
    const float* c_ow   = (const float*)d_in[22];
    const float* c_ob   = (const float*)d_in[23];
    const float* c_fg   = (const float*)d_in[24];
    const float* c_fb   = (const float*)d_in[25];
    const float* c_fw1  = (const float*)d_in[26];
    const float* c_fb1  = (const float*)d_in[27];
    const float* c_fw2  = (const float*)d_in[28];
    const float* c_fb2  = (const float*)d_in[29];
    const float* s_ln_g = (const float*)d_in[30];
    const float* s_ln_b = (const float*)d_in[31];
    const float* s_qw   = (const float*)d_in[32];
    const float* s_kw   = (const float*)d_in[33];
    const float* s_vw   = (const float*)d_in[34];
    const float* s_ow   = (const float*)d_in[35];
    const float* s_ob   = (const float*)d_in[36];
    const float* s_fg   = (const float*)d_in[37];
    const float* s_fb   = (const float*)d_in[38];
    const float* s_fw1  = (const float*)d_in[39];
    const float* s_fb1  = (const float*)d_in[40];
    const float* s_fw2  = (const float*)d_in[41];
    const float* s_fb2  = (const float*)d_in[42];
    const float* q_w1   = (const float*)d_in[43];
    const float* q_b1   = (const float*)d_in[44];
    const float* q_w2   = (const float*)d_in[45];
    const float* q_b2   = (const float*)d_in[46];
    const float* norm_g = (const float*)d_in[47];
    const float* norm_b = (const float*)d_in[48];
    const float* out_w  = (const float*)d_in[49];
    const float* out_b  = (const float*)d_in[50];
    float* out = (float*)d_out;

    // ---- workspace carve (256B aligned) ----
    char* p = (char*)d_ws;
    auto alloc = [&](size_t bytes) { char* r = p; p += (bytes + 255) & ~(size_t)255; return r; };
    short* rgbf  = (short*)alloc((size_t)BSV * 256 * 2);
    short* hall  = (short*)alloc((size_t)DD * BSV * 32 * 2);
    short* kvall = (short*)alloc((size_t)4 * BSV * 512 * 2);   // 134 MB
    short* a_in  = (short*)alloc((size_t)BSV * 256 * 2);       // preamble temp
    short* obb   = (short*)alloc((size_t)BS * 256 * 2);
    short* xq    = (short*)alloc((size_t)BS * 256 * 2);
    short* hb    = (short*)alloc((size_t)BS * 256 * 2);
    short* ffh   = (short*)alloc((size_t)BS * 1024 * 2);
    short* catb  = (short*)alloc((size_t)BS * 384 * 2);
    short* qkv   = (short*)alloc((size_t)BS * 768 * 2);        // also rgbp alias
    short* rgbp  = qkv;
    float* qf    = (float*)alloc((size_t)BS * 256 * 4);
    float* fq    = (float*)alloc((size_t)BS * 256 * 4);
    float* ipts  = (float*)alloc((size_t)BS * 63 * 4);
    float* ivw   = (float*)alloc((size_t)BB * 27 * 4);
    // weights (bf16, transposed [N,Kpad])
    short* w1T   = (short*)alloc(256 * 64 * 2);
    short* w2T   = (short*)alloc(256 * 256 * 2);
    short* qwT   = (short*)alloc((size_t)DD * 256 * 256 * 2);
    short* kvpT  = (short*)alloc((size_t)DD * 512 * 288 * 2);
    short* aw1T  = (short*)alloc((size_t)DD * 32 * 256 * 2);
    short* aw2T  = (short*)alloc((size_t)DD * 256 * 32 * 2);
    short* owT   = (short*)alloc((size_t)DD * 256 * 256 * 2);
    short* fw1T  = (short*)alloc((size_t)DD * 1024 * 256 * 2);
    short* fw2T  = (short*)alloc((size_t)DD * 256 * 1024 * 2);
    short* sqkvT = (short*)alloc((size_t)DD * 768 * 256 * 2);
    short* sowT  = (short*)alloc((size_t)DD * 256 * 256 * 2);
    short* sfw1T = (short*)alloc((size_t)DD * 1024 * 256 * 2);
    short* sfw2T = (short*)alloc((size_t)DD * 256 * 1024 * 2);
    short* qw1T  = (short*)alloc((size_t)4 * 256 * 384 * 2);
    short* qw2T  = (short*)alloc((size_t)4 * 256 * 256 * 2);

    // ---- weight conversion ----
    dim3 wb(32, 8);
    wconv<<<dim3(8, 2, 1), wb, 0, stream>>>(rgbfeat_w1, w1T, 35, 256, 64, 0, 0);
    wconv<<<dim3(8, 8, 1), wb, 0, stream>>>(rgbfeat_w2, w2T, 256, 256, 256, 0, 0);
    wconv<<<dim3(8, 8, DD), wb, 0, stream>>>(c_qw, qwT, 256, 256, 256, 65536, 65536);
    wconv<<<dim3(8, 8, DD), wb, 0, stream>>>(c_kw, kvpT, 256, 256, 288, 65536, 147456);
    wconv<<<dim3(8, 1, DD), wb, 0, stream>>>(c_pw2, kvpT + 256, 32, 256, 288, 8192, 147456);
    wconv<<<dim3(8, 8, DD), wb, 0, stream>>>(c_vw, kvpT + 256 * 288, 256, 256, 288, 65536, 147456);
    wconv<<<dim3(8, 1, DD), wb, 0, stream>>>(c_pw2, kvpT + 256 * 288 + 256, 32, 256, 288, 8192, 147456);
    wconv<<<dim3(1, 8, DD), wb, 0, stream>>>(c_aw1, aw1T, 256, 32, 256, 8192, 8192);
    wconv<<<dim3(8, 1, DD), wb, 0, stream>>>(c_aw2, aw2T, 32, 256, 32, 8192, 8192);
    wconv<<<dim3(8, 8, DD), wb, 0, stream>>>(c_ow, owT, 256, 256, 256, 65536, 65536);
    wconv<<<dim3(32, 8, DD), wb, 0, stream>>>(c_fw1, fw1T, 256, 1024, 256, 262144, 262144);
    wconv<<<dim3(8, 32, DD), wb, 0, stream>>>(c_fw2, fw2T, 1024, 256, 1024, 262144, 262144);
    wconv<<<dim3(8, 8, DD), wb, 0, stream>>>(s_qw, sqkvT, 256, 256, 256, 65536, 196608);
    wconv<<<dim3(8, 8, DD), wb, 0, stream>>>(s_kw, sqkvT + 65536, 256, 256, 256, 65536, 196608);
    wconv<<<dim3(8, 8, DD), wb, 0, stream>>>(s_vw, sqkvT + 131072, 256, 256, 256, 65536, 196608);
    wconv<<<dim3(8, 8, DD), wb, 0, stream>>>(s_ow, sowT, 256, 256, 256, 65536, 65536);
    wconv<<<dim3(32, 8, DD), wb, 0, stream>>>(s_fw1, sfw1T, 256, 1024, 256, 262144, 262144);
    wconv<<<dim3(8, 32, DD), wb, 0, stream>>>(s_fw2, sfw2T, 1024, 256, 1024, 262144, 262144);
    wconv<<<dim3(8, 12, 4), wb, 0, stream>>>(q_w1, qw1T, 346, 256, 384, 88576, 98304);
    wconv<<<dim3(8, 8, 4), wb, 0, stream>>>(q_w2, qw2T, 256, 256, 256, 65536, 65536);

    // ---- preamble ----
    penc_pts<<<(BS + 255) / 256, 256, 0, stream>>>(pts, ipts);
    penc_views<<<1, 64, 0, stream>>>(ray_d, ivw);
    catfill<<<(BS * 128) / 256, 256, 0, stream>>>(ipts, ivw, catb);
    rgbconv<<<(BSV * 64) / 256, 256, 0, stream>>>(rgb_feat, rgbp);
    hallk<<<(DD * BSV * 32) / 256, 256, 0, stream>>>(ray_diff, c_pw1, c_pb1, hall);
    GEMM_BF(128, 128, 64, 64, rgbp, w1T, rgbfeat_b1, a_in, BSV, 256, 64, 256, 1);
    GEMM_BF(128, 128, 64, 64, a_in, w2T, rgbfeat_b2, rgbf, BSV, 256, 256, 256, 0);
    vmaxln<<<BS, 256, 0, stream>>>(rgbf, c_ln_g, c_ln_b, fq, xq);
    kvbatch<<<dim3(4, 4, 256), 256, 0, stream>>>(rgbf, hall, kvpT, kvall, 0);

    for (int i = 0; i < DD; i++) {
        int j = i >> 1;
        if (i == 4)
            kvbatch<<<dim3(4, 4, 256), 256, 0, stream>>>(rgbf, hall, kvpT, kvall, 4);
        // ---- cross transformer ----
        if (i > 0)
            lnormB<<<BS, 256, 0, stream>>>(fq, c_ln_g + i * WW, c_ln_b + i * WW, xq, 1e-6f);
        GEMM_F(64, 64, 32, 32, xq, qwT + (size_t)i * 65536, nullptr, nullptr, qf, BS, 256, 256, 0);
        crossattn<<<BSV / 64, 256, 0, stream>>>(kvall + (size_t)(i & 3) * BSV * 512, qf, maskp,
            aw1T + (size_t)i * 8192, c_ab1 + i * 32,
            aw2T + (size_t)i * 8192, c_ab2 + i * 256, obb);
        GEMM_F(64, 64, 32, 32, obb, owT + (size_t)i * 65536, c_ob + i * 256, fq, fq, BS, 256, 256, 0);
        lnormB<<<BS, 256, 0, stream>>>(fq, c_fg + i * WW, c_fb + i * WW, hb, 1e-6f);
        GEMM_BF(64, 128, 32, 64, hb, fw1T + (size_t)i * 262144, c_fb1 + i * 1024, ffh, BS, 1024, 256, 1024, 1);
        if ((i & 1) == 0) {
            GEMM_F2(64, 64, 32, 32, ffh, fw2T + (size_t)i * 262144, c_fb2 + i * 256, fq, fq,
                    catb, 384, BS, 256, 1024, 0);
            GEMM_BF(64, 64, 32, 32, catb, qw1T + (size_t)j * 98304, q_b1 + j * 256, hb, BS, 256, 384, 256, 1);
            GEMM_F(64, 64, 32, 32, hb, qw2T + (size_t)j * 65536, q_b2 + j * 256, nullptr, fq, BS, 256, 256, 0);
        } else {
            GEMM_F(64, 64, 32, 32, ffh, fw2T + (size_t)i * 262144, c_fb2 + i * 256, fq, fq, BS, 256, 1024, 0);
        }
        // ---- self transformer ----
        lnormB<<<BS, 256, 0, stream>>>(fq, s_ln_g + i * WW, s_ln_b + i * WW, xq, 1e-6f);
        GEMM_BF(64, 128, 32, 64, xq, sqkvT + (size_t)i * 196608, nullptr, qkv, BS, 768, 256, 768, 0);
        attn_mfma<<<BB * 4, 64, 0, stream>>>(qkv, obb);
        GEMM_F(64, 64, 32, 32, obb, sowT + (size_t)i * 65536, s_ob + i * 256, fq, fq, BS, 256, 256, 0);
        lnormB<<<BS, 256, 0, stream>>>(fq, s_fg + i * WW, s_fb + i * WW, hb, 1e-6f);
        GEMM_BF(64, 128, 32, 64, hb, sfw1T + (size_t)i * 262144, s_fb1 + i * 1024, ffh, BS, 1024, 256, 1024, 1);
        GEMM_F(64, 64, 32, 32, ffh, sfw2T + (size_t)i * 262144, s_fb2 + i * 256, fq, fq, BS, 256, 1024, 0);
    }

    // ---- final norm + head ----
    lnormB<<<BS, 256, 0, stream>>>(fq, norm_g, norm_b, hb, 1e-5f);
    headk<<<BB, 256, 0, stream>>>(hb, out_w, out_b, out);
}